// Round 2
// baseline (812.203 us; speedup 1.0000x reference)
//
#include <hip/hip_runtime.h>

typedef __bf16 bf16;
typedef __bf16 bf16x8 __attribute__((ext_vector_type(8)));
typedef __bf16 bf16x4 __attribute__((ext_vector_type(4)));
typedef float f32x4 __attribute__((ext_vector_type(4)));

#define SEQ 4096
#define QKV_LD 6144
#define HNUM 16

__device__ __forceinline__ void async16(const bf16* g, bf16* l) {
    __builtin_amdgcn_global_load_lds((const __attribute__((address_space(1))) void*)g,
                                     (__attribute__((address_space(3))) void*)l, 16, 0, 0);
}

// ---------- C[M][N] = A[M][K] @ B[N][K]^T ; f32 accum ----------
// A_F32/B_F32: input dtype (f32 -> VGPR-convert staging; bf16 -> global_load_lds)
// C_F32: output dtype.
template <int A_F32, int B_F32, int C_F32>
__global__ __launch_bounds__(256) void gemm_nt(const void* __restrict__ Ap,
                                               const void* __restrict__ Bp,
                                               void* __restrict__ Cp,
                                               int M, int N, int K) {
    __shared__ __align__(16) bf16 sA[128 * 32];
    __shared__ __align__(16) bf16 sB[128 * 32];
    const int tid  = threadIdx.x;
    const int wave = tid >> 6, lane = tid & 63;
    const int qd = lane >> 4, ln = lane & 15;
    const int bm = blockIdx.x * 128, bn = blockIdx.y * 128;
    const int wm = (wave >> 1) * 64, wn = (wave & 1) * 64;

    // staging layout: row srow (0..63) + 64, 8-elem chunk at scol
    const int srow = wave * 16 + (lane >> 2);
    const int scol = (lane & 3) * 8;
    const size_t rowoff = (size_t)srow * K + scol;
    const size_t rowskip = (size_t)64 * K;

    const bf16* Ab = (const bf16*)Ap + (size_t)bm * K + rowoff;
    const bf16* Bb = (const bf16*)Bp + (size_t)bn * K + rowoff;
    const float* Af = (const float*)Ap + (size_t)bm * K + rowoff;
    const float* Bf = (const float*)Bp + (size_t)bn * K + rowoff;
    bf16* sAd0 = &sA[(wave * 16) * 32];
    bf16* sAd1 = &sA[(64 + wave * 16) * 32];
    bf16* sBd0 = &sB[(wave * 16) * 32];
    bf16* sBd1 = &sB[(64 + wave * 16) * 32];
    bf16* sAw0 = &sA[srow * 32 + scol];
    bf16* sAw1 = &sA[(64 + srow) * 32 + scol];
    bf16* sBw0 = &sB[srow * 32 + scol];
    bf16* sBw1 = &sB[(64 + srow) * 32 + scol];

    f32x4 acc[4][4] = {};
    for (int k0 = 0; k0 < K; k0 += 32) {
        if (A_F32) {
            f32x4 u0 = *(const f32x4*)(Af + k0);
            f32x4 u1 = *(const f32x4*)(Af + k0 + 4);
            f32x4 u2 = *(const f32x4*)(Af + rowskip + k0);
            f32x4 u3 = *(const f32x4*)(Af + rowskip + k0 + 4);
            bf16x8 w0, w1;
#pragma unroll
            for (int i = 0; i < 4; i++) { w0[i] = (bf16)u0[i]; w0[4 + i] = (bf16)u1[i];
                                          w1[i] = (bf16)u2[i]; w1[4 + i] = (bf16)u3[i]; }
            *(bf16x8*)sAw0 = w0;
            *(bf16x8*)sAw1 = w1;
        } else {
            async16(Ab + k0, sAd0);
            async16(Ab + rowskip + k0, sAd1);
        }
        if (B_F32) {
            f32x4 u0 = *(const f32x4*)(Bf + k0);
            f32x4 u1 = *(const f32x4*)(Bf + k0 + 4);
            f32x4 u2 = *(const f32x4*)(Bf + rowskip + k0);
            f32x4 u3 = *(const f32x4*)(Bf + rowskip + k0 + 4);
            bf16x8 w0, w1;
#pragma unroll
            for (int i = 0; i < 4; i++) { w0[i] = (bf16)u0[i]; w0[4 + i] = (bf16)u1[i];
                                          w1[i] = (bf16)u2[i]; w1[4 + i] = (bf16)u3[i]; }
            *(bf16x8*)sBw0 = w0;
            *(bf16x8*)sBw1 = w1;
        } else {
            async16(Bb + k0, sBd0);
            async16(Bb + rowskip + k0, sBd1);
        }
        __syncthreads();
        bf16x8 af[4], bfr[4];
#pragma unroll
        for (int i = 0; i < 4; i++)
            af[i] = *(const bf16x8*)&sA[(wm + i * 16 + ln) * 32 + qd * 8];
#pragma unroll
        for (int j = 0; j < 4; j++)
            bfr[j] = *(const bf16x8*)&sB[(wn + j * 16 + ln) * 32 + qd * 8];
#pragma unroll
        for (int i = 0; i < 4; i++)
#pragma unroll
            for (int j = 0; j < 4; j++)
                acc[i][j] = __builtin_amdgcn_mfma_f32_16x16x32_bf16(af[i], bfr[j], acc[i][j], 0, 0, 0);
        __syncthreads();
    }
    // C/D layout: col = lane&15, row = quad*4 + reg
    const size_t cbase = (size_t)(bm + wm + qd * 4) * N + (bn + wn + ln);
#pragma unroll
    for (int i = 0; i < 4; i++)
#pragma unroll
        for (int j = 0; j < 4; j++)
#pragma unroll
            for (int r = 0; r < 4; r++) {
                size_t idx = cbase + (size_t)(i * 16 + r) * N + j * 16;
                if (C_F32) ((float*)Cp)[idx] = acc[i][j][r];
                else       ((bf16*)Cp)[idx] = (bf16)acc[i][j][r];
            }
}

// ---------- RoPE in-place on Q,K sections of QKV [4096][6144] (bf16) ----------
__global__ __launch_bounds__(256) void rope_k(bf16* __restrict__ QKV) {
    const int s  = blockIdx.x;
    const int t  = threadIdx.x;
    const int hh = (blockIdx.y << 2) + (t >> 6);  // 0..31 (Q heads then K heads)
    const int d  = t & 63;
    bf16* p = QKV + (size_t)s * QKV_LD + hh * 128 + d;
    float x0 = (float)p[0];
    float x1 = (float)p[64];
    float inv_freq = powf(10000.0f, -(float)d * (1.0f / 64.0f));
    float ang = (float)s * inv_freq;
    float c = cosf(ang), sn = sinf(ang);
    p[0]  = (bf16)(x0 * c - x1 * sn);
    p[64] = (bf16)(x1 * c + x0 * sn);
}

// ---------- causal flash attention (bf16 in/out) ----------
// block: 256 thr = 4 waves; 64 q rows/block (16 per wave); KV tiles of 64.
// S computed TRANSPOSED (mfma(A=K, B=Q) -> S^T) so P stores pack into b64.
// All LDS tiles use XOR-swizzled 16B blocks (blk ^= row&7) -> conflict-free.
__global__ __launch_bounds__(256) void flash_attn(const bf16* __restrict__ QKV,
                                                  bf16* __restrict__ O) {
    __shared__ __align__(16) bf16 sK[64 * 128];   // [kv][d]
    __shared__ __align__(16) bf16 sV[128 * 64];   // [d][kv] (transposed)
    __shared__ __align__(16) bf16 sP[4][16 * 64]; // per-wave P [q][kv]
    const int tid  = threadIdx.x;
    const int wave = tid >> 6, lane = tid & 63;
    const int qd = lane >> 4, ln = lane & 15;
    const int h = blockIdx.y;
    const int qtile = gridDim.x - 1 - blockIdx.x;  // heaviest blocks first
    const int qbase = qtile * 64;
    const int qw = qbase + wave * 16;              // this wave's 16 q rows

    // Q fragment (B-operand): lane holds Q[qw+ln][ks*32 + qd*8 + j]
    const bf16* Qg = QKV + (size_t)(qw + ln) * QKV_LD + h * 128;
    bf16x8 Qf[4];
#pragma unroll
    for (int ks = 0; ks < 4; ks++) Qf[ks] = *(const bf16x8*)(Qg + ks * 32 + qd * 8);

    f32x4 Oacc[8] = {};
    float m_i = -1e30f, l_i = 0.0f;  // state for q row (qw + ln), replicated per quad

    const int krow = tid >> 4;        // K staging: kv row within 16-row slab
    const int kblk = tid & 15;        // 16B block along d
    const int vd   = tid & 127;       // V staging: d row
    const int vkb0 = (tid >> 7) * 4;  // kv-block group
    const bf16* Kg = QKV + 2048 + h * 128;
    const bf16* Vg = QKV + 4096 + h * 128;
    const float scale = 0.08838834764831843f;  // 1/sqrt(128)

    for (int kt = 0; kt <= qtile; kt++) {
        const int kbase = kt * 64;
        __syncthreads();
        // stage K [64][128], swizzled
#pragma unroll
        for (int rr = 0; rr < 4; rr++) {
            int kv = rr * 16 + krow;
            bf16x8 k8 = *(const bf16x8*)(Kg + (size_t)(kbase + kv) * QKV_LD + kblk * 8);
            *(bf16x8*)&sK[kv * 128 + ((kblk ^ (kv & 7)) * 8)] = k8;
        }
        // stage V transposed [d][kv], swizzled; gather 8 rows per b128 write
#pragma unroll
        for (int u = 0; u < 4; u++) {
            int kvb = vkb0 + u;
            bf16x8 v8;
#pragma unroll
            for (int j = 0; j < 8; j++)
                v8[j] = Vg[(size_t)(kbase + kvb * 8 + j) * QKV_LD + vd];
            *(bf16x8*)&sV[vd * 64 + ((kvb ^ (vd & 7)) * 8)] = v8;
        }
        __syncthreads();

        // S^T tiles: Sacc[j] rows kv = kbase + j*16 + qd*4 + r ; col q = qw + ln
        f32x4 Sacc[4] = {};
#pragma unroll
        for (int ks = 0; ks < 4; ks++)
#pragma unroll
            for (int j = 0; j < 4; j++) {
                bf16x8 af = *(const bf16x8*)&sK[(j * 16 + ln) * 128 + (((ks * 4 + qd) ^ (ln & 7)) * 8)];
                Sacc[j] = __builtin_amdgcn_mfma_f32_16x16x32_bf16(af, Qf[ks], Sacc[j], 0, 0, 0);
            }
#pragma unroll
        for (int j = 0; j < 4; j++)
#pragma unroll
            for (int r = 0; r < 4; r++) Sacc[j][r] *= scale;
        if (kt == qtile) {  // causal mask on diagonal tile: kv > q -> -inf
#pragma unroll
            for (int j = 0; j < 4; j++)
#pragma unroll
                for (int r = 0; r < 4; r++)
                    if (kbase + j * 16 + qd * 4 + r > qw + ln) Sacc[j][r] = -1e30f;
        }
        float rmax = -1e30f;
#pragma unroll
        for (int j = 0; j < 4; j++)
#pragma unroll
            for (int r = 0; r < 4; r++) rmax = fmaxf(rmax, Sacc[j][r]);
        rmax = fmaxf(rmax, __shfl_xor(rmax, 16));
        rmax = fmaxf(rmax, __shfl_xor(rmax, 32));
        float mnew = fmaxf(m_i, rmax);
        float alpha = __expf(m_i - mnew);
        m_i = mnew;

        float psum = 0.0f;
#pragma unroll
        for (int j = 0; j < 4; j++) {
            bf16x4 p4;
#pragma unroll
            for (int r = 0; r < 4; r++) {
                float p = __expf(Sacc[j][r] - m_i);
                psum += p;
                p4[r] = (bf16)p;
            }
            // store P[q=ln][kv=j*16+qd*4 ..+4] as one b64, swizzled 16B blocks
            int blk = (j * 2 + (qd >> 1)) ^ (ln & 7);
            *(bf16x4*)&sP[wave][ln * 64 + blk * 8 + (qd & 1) * 4] = p4;
        }
        psum += __shfl_xor(psum, 16);
        psum += __shfl_xor(psum, 32);
        l_i = l_i * alpha + psum;

        // rescale O (rows q = qd*4+r): fetch alpha of those rows from quad lanes
        float a4[4];
#pragma unroll
        for (int r = 0; r < 4; r++) a4[r] = __shfl(alpha, (lane & 48) | (qd * 4 + r));
#pragma unroll
        for (int dt = 0; dt < 8; dt++)
#pragma unroll
            for (int r = 0; r < 4; r++) Oacc[dt][r] *= a4[r];

        // PV: A = P[q][kv], B = V[kv][d] (from transposed sV)
#pragma unroll
        for (int ks = 0; ks < 2; ks++) {
            bf16x8 pf = *(const bf16x8*)&sP[wave][ln * 64 + (((ks * 4 + qd) ^ (ln & 7)) * 8)];
#pragma unroll
            for (int dt = 0; dt < 8; dt++) {
                bf16x8 vf = *(const bf16x8*)&sV[(dt * 16 + ln) * 64 + (((ks * 4 + qd) ^ (ln & 7)) * 8)];
                Oacc[dt] = __builtin_amdgcn_mfma_f32_16x16x32_bf16(pf, vf, Oacc[dt], 0, 0, 0);
            }
        }
    }
    // epilogue: O rows q = qw + qd*4 + r, col = h*128 + dt*16 + ln
    float linv[4];
#pragma unroll
    for (int r = 0; r < 4; r++)
        linv[r] = 1.0f / __shfl(l_i, (lane & 48) | (qd * 4 + r));
    bf16* Ob = O + (size_t)(qw + qd * 4) * 2048 + h * 128 + ln;
#pragma unroll
    for (int dt = 0; dt < 8; dt++)
#pragma unroll
        for (int r = 0; r < 4; r++)
            Ob[(size_t)r * 2048 + dt * 16] = (bf16)(Oacc[dt][r] * linv[r]);
}

extern "C" void kernel_launch(void* const* d_in, const int* in_sizes, int n_in,
                              void* d_out, int out_size, void* d_ws, size_t ws_size,
                              hipStream_t stream) {
    const float* X    = (const float*)d_in[0];  // [4096][2048] f32
    const float* Wqkv = (const float*)d_in[1];  // [6144][2048] f32
    const float* Wo   = (const float*)d_in[2];  // [2048][2048] f32
    float* out = (float*)d_out;                 // [4096][2048] f32
    bf16* QKV = (bf16*)d_ws;                    // [4096][6144] bf16
    bf16* ATT = QKV + (size_t)4096 * 6144;      // [4096][2048] bf16

    // QKV projection: f32 in, bf16 out
    gemm_nt<1, 1, 0><<<dim3(32, 48), 256, 0, stream>>>(X, Wqkv, QKV, 4096, 6144, 2048);
    rope_k<<<dim3(4096, 8), 256, 0, stream>>>(QKV);
    flash_attn<<<dim3(64, HNUM), 256, 0, stream>>>(QKV, ATT);
    // out projection: A bf16 (async staging), B f32, C f32
    gemm_nt<0, 1, 1><<<dim3(32, 16), 256, 0, stream>>>(ATT, Wo, out, 4096, 2048, 2048);
}

// Round 3
// 503.048 us; speedup vs baseline: 1.6146x; 1.6146x over previous
//
#include <hip/hip_runtime.h>

typedef __bf16 bf16;
typedef __bf16 bf16x8 __attribute__((ext_vector_type(8)));
typedef __bf16 bf16x4 __attribute__((ext_vector_type(4)));
typedef float f32x4 __attribute__((ext_vector_type(4)));

#define SEQ 4096
#define QKV_LD 6144
#define HNUM 16

__device__ __forceinline__ void async16(const bf16* g, bf16* l) {
    __builtin_amdgcn_global_load_lds((const __attribute__((address_space(1))) void*)g,
                                     (__attribute__((address_space(3))) void*)l, 16, 0, 0);
}

// ---------- f32 -> bf16 cast, 8 elems/thread ----------
__global__ __launch_bounds__(256) void cast_f32_bf16(const float* __restrict__ src,
                                                     bf16* __restrict__ dst, int n) {
    int i = (blockIdx.x * 256 + threadIdx.x) * 8;
    if (i >= n) return;
    f32x4 a = *(const f32x4*)(src + i);
    f32x4 b = *(const f32x4*)(src + i + 4);
    bf16x8 w;
#pragma unroll
    for (int j = 0; j < 4; j++) { w[j] = (bf16)a[j]; w[4 + j] = (bf16)b[j]; }
    *(bf16x8*)(dst + i) = w;
}

// ---------- C[M][N] = A[M][K] @ B[N][K]^T ; f32 accum ----------
// A_F32/B_F32: input dtype (f32 -> VGPR-convert staging; bf16 -> global_load_lds)
template <int A_F32, int B_F32, int C_F32>
__global__ __launch_bounds__(256) void gemm_nt(const void* __restrict__ Ap,
                                               const void* __restrict__ Bp,
                                               void* __restrict__ Cp,
                                               int M, int N, int K) {
    __shared__ __align__(16) bf16 sA[128 * 32];
    __shared__ __align__(16) bf16 sB[128 * 32];
    const int tid  = threadIdx.x;
    const int wave = tid >> 6, lane = tid & 63;
    const int qd = lane >> 4, ln = lane & 15;
    const int bm = blockIdx.x * 128, bn = blockIdx.y * 128;
    const int wm = (wave >> 1) * 64, wn = (wave & 1) * 64;

    const int srow = wave * 16 + (lane >> 2);
    const int scol = (lane & 3) * 8;
    const size_t rowoff = (size_t)srow * K + scol;
    const size_t rowskip = (size_t)64 * K;

    const bf16* Ab = (const bf16*)Ap + (size_t)bm * K + rowoff;
    const bf16* Bb = (const bf16*)Bp + (size_t)bn * K + rowoff;
    const float* Af = (const float*)Ap + (size_t)bm * K + rowoff;
    const float* Bf = (const float*)Bp + (size_t)bn * K + rowoff;
    bf16* sAd0 = &sA[(wave * 16) * 32];
    bf16* sAd1 = &sA[(64 + wave * 16) * 32];
    bf16* sBd0 = &sB[(wave * 16) * 32];
    bf16* sBd1 = &sB[(64 + wave * 16) * 32];
    bf16* sAw0 = &sA[srow * 32 + scol];
    bf16* sAw1 = &sA[(64 + srow) * 32 + scol];
    bf16* sBw0 = &sB[srow * 32 + scol];
    bf16* sBw1 = &sB[(64 + srow) * 32 + scol];

    f32x4 acc[4][4] = {};
    for (int k0 = 0; k0 < K; k0 += 32) {
        if (A_F32) {
            f32x4 u0 = *(const f32x4*)(Af + k0);
            f32x4 u1 = *(const f32x4*)(Af + k0 + 4);
            f32x4 u2 = *(const f32x4*)(Af + rowskip + k0);
            f32x4 u3 = *(const f32x4*)(Af + rowskip + k0 + 4);
            bf16x8 w0, w1;
#pragma unroll
            for (int i = 0; i < 4; i++) { w0[i] = (bf16)u0[i]; w0[4 + i] = (bf16)u1[i];
                                          w1[i] = (bf16)u2[i]; w1[4 + i] = (bf16)u3[i]; }
            *(bf16x8*)sAw0 = w0;
            *(bf16x8*)sAw1 = w1;
        } else {
            async16(Ab + k0, sAd0);
            async16(Ab + rowskip + k0, sAd1);
        }
        if (B_F32) {
            f32x4 u0 = *(const f32x4*)(Bf + k0);
            f32x4 u1 = *(const f32x4*)(Bf + k0 + 4);
            f32x4 u2 = *(const f32x4*)(Bf + rowskip + k0);
            f32x4 u3 = *(const f32x4*)(Bf + rowskip + k0 + 4);
            bf16x8 w0, w1;
#pragma unroll
            for (int i = 0; i < 4; i++) { w0[i] = (bf16)u0[i]; w0[4 + i] = (bf16)u1[i];
                                          w1[i] = (bf16)u2[i]; w1[4 + i] = (bf16)u3[i]; }
            *(bf16x8*)sBw0 = w0;
            *(bf16x8*)sBw1 = w1;
        } else {
            async16(Bb + k0, sBd0);
            async16(Bb + rowskip + k0, sBd1);
        }
        __syncthreads();
        bf16x8 af[4], bfr[4];
#pragma unroll
        for (int i = 0; i < 4; i++)
            af[i] = *(const bf16x8*)&sA[(wm + i * 16 + ln) * 32 + qd * 8];
#pragma unroll
        for (int j = 0; j < 4; j++)
            bfr[j] = *(const bf16x8*)&sB[(wn + j * 16 + ln) * 32 + qd * 8];
#pragma unroll
        for (int i = 0; i < 4; i++)
#pragma unroll
            for (int j = 0; j < 4; j++)
                acc[i][j] = __builtin_amdgcn_mfma_f32_16x16x32_bf16(af[i], bfr[j], acc[i][j], 0, 0, 0);
        __syncthreads();
    }
    const size_t cbase = (size_t)(bm + wm + qd * 4) * N + (bn + wn + ln);
#pragma unroll
    for (int i = 0; i < 4; i++)
#pragma unroll
        for (int j = 0; j < 4; j++)
#pragma unroll
            for (int r = 0; r < 4; r++) {
                size_t idx = cbase + (size_t)(i * 16 + r) * N + j * 16;
                if (C_F32) ((float*)Cp)[idx] = acc[i][j][r];
                else       ((bf16*)Cp)[idx] = (bf16)acc[i][j][r];
            }
}

// ---------- RoPE in-place on Q,K sections of QKV [4096][6144] (bf16) ----------
__global__ __launch_bounds__(256) void rope_k(bf16* __restrict__ QKV) {
    const int s  = blockIdx.x;
    const int t  = threadIdx.x;
    const int hh = (blockIdx.y << 2) + (t >> 6);
    const int d  = t & 63;
    bf16* p = QKV + (size_t)s * QKV_LD + hh * 128 + d;
    float x0 = (float)p[0];
    float x1 = (float)p[64];
    float inv_freq = powf(10000.0f, -(float)d * (1.0f / 64.0f));
    float ang = (float)s * inv_freq;
    float c = cosf(ang), sn = sinf(ang);
    p[0]  = (bf16)(x0 * c - x1 * sn);
    p[64] = (bf16)(x1 * c + x0 * sn);
}

// ---------- causal flash attention, software-pipelined staging ----------
// 256 thr = 4 waves; 64 q rows/block (16/wave); KV tiles of 64.
// Tile kt+1's K/V are loaded into VGPRs during tile kt's compute; committed
// to LDS (swizzled) at iteration top. No global latency inside the barriers.
__global__ __launch_bounds__(256, 3) void flash_attn(const bf16* __restrict__ QKV,
                                                     bf16* __restrict__ O) {
    __shared__ __align__(16) bf16 sK[64 * 128];   // [kv][d], 16B-block swizzle
    __shared__ __align__(16) bf16 sV[128 * 64];   // [d][kv] transposed, swizzled
    __shared__ __align__(16) bf16 sP[4][16 * 64]; // per-wave P [q][kv]
    const int tid  = threadIdx.x;
    const int wave = tid >> 6, lane = tid & 63;
    const int qd = lane >> 4, ln = lane & 15;
    const int h  = blockIdx.x;
    const int by = blockIdx.y;
    const int qtile = (by < 32) ? (63 - by) : (by - 32);  // paired: CU load sums constant
    const int qbase = qtile * 64;
    const int qw = qbase + wave * 16;
    const int nkv = qtile + 1;

    const bf16* Qg = QKV + (size_t)(qw + ln) * QKV_LD + h * 128;
    bf16x8 Qf[4];
#pragma unroll
    for (int ks = 0; ks < 4; ks++) Qf[ks] = *(const bf16x8*)(Qg + ks * 32 + qd * 8);

    f32x4 Oacc[8] = {};
    float m_i = -1e30f, l_i = 0.0f;

    const int krow = tid >> 4;   // K staging: kv row within 16-row slab (0..15)
    const int kblk = tid & 15;   // 16B block along d
    const bf16* Kg = QKV + 2048 + h * 128;
    const bf16* Vg = QKV + 4096 + h * 128;
    const float scale = 0.08838834764831843f;  // 1/sqrt(128)

    // prefetch registers
    bf16x8 Kpre[4], Vpre[4];
#pragma unroll
    for (int rr = 0; rr < 4; rr++)
        Kpre[rr] = *(const bf16x8*)(Kg + (size_t)(rr * 16 + krow) * QKV_LD + kblk * 8);
    // V: lane = kv row, wave covers d in [wave*32, wave*32+32) -> one 64B line/lane
#pragma unroll
    for (int u = 0; u < 4; u++)
        Vpre[u] = *(const bf16x8*)(Vg + (size_t)lane * QKV_LD + wave * 32 + u * 8);

    for (int kt = 0; kt < nkv; kt++) {
        const int kbase = kt * 64;
        // commit staged tile to LDS
#pragma unroll
        for (int rr = 0; rr < 4; rr++) {
            int kv = rr * 16 + krow;
            *(bf16x8*)&sK[kv * 128 + ((kblk ^ (kv & 7)) * 8)] = Kpre[rr];
        }
#pragma unroll
        for (int u = 0; u < 4; u++)
#pragma unroll
            for (int jj = 0; jj < 8; jj++) {
                int d = wave * 32 + u * 8 + jj;  // d&7 == jj
                sV[d * 64 + (((lane >> 3) ^ jj) * 8) + (lane & 7)] = Vpre[u][jj];
            }
        __syncthreads();
        // prefetch next tile (overlaps with compute below)
        if (kt + 1 < nkv) {
            const int nb = kbase + 64;
#pragma unroll
            for (int rr = 0; rr < 4; rr++)
                Kpre[rr] = *(const bf16x8*)(Kg + (size_t)(nb + rr * 16 + krow) * QKV_LD + kblk * 8);
#pragma unroll
            for (int u = 0; u < 4; u++)
                Vpre[u] = *(const bf16x8*)(Vg + (size_t)(nb + lane) * QKV_LD + wave * 32 + u * 8);
        }
        if (kbase <= qw + 15) {  // wave-uniform: skip fully-masked tiles
            // S^T: rows kv = kbase + j*16 + qd*4 + r ; col q = qw + ln
            f32x4 Sacc[4] = {};
#pragma unroll
            for (int ks = 0; ks < 4; ks++)
#pragma unroll
                for (int j = 0; j < 4; j++) {
                    bf16x8 af = *(const bf16x8*)&sK[(j * 16 + ln) * 128 + (((ks * 4 + qd) ^ (ln & 7)) * 8)];
                    Sacc[j] = __builtin_amdgcn_mfma_f32_16x16x32_bf16(af, Qf[ks], Sacc[j], 0, 0, 0);
                }
#pragma unroll
            for (int j = 0; j < 4; j++)
#pragma unroll
                for (int r = 0; r < 4; r++) Sacc[j][r] *= scale;
            if (kbase + 63 > qw) {  // diagonal: mask kv > q
#pragma unroll
                for (int j = 0; j < 4; j++)
#pragma unroll
                    for (int r = 0; r < 4; r++)
                        if (kbase + j * 16 + qd * 4 + r > qw + ln) Sacc[j][r] = -1e30f;
            }
            float rmax = -1e30f;
#pragma unroll
            for (int j = 0; j < 4; j++)
#pragma unroll
                for (int r = 0; r < 4; r++) rmax = fmaxf(rmax, Sacc[j][r]);
            rmax = fmaxf(rmax, __shfl_xor(rmax, 16));
            rmax = fmaxf(rmax, __shfl_xor(rmax, 32));
            float mnew = fmaxf(m_i, rmax);
            float alpha = __expf(m_i - mnew);
            m_i = mnew;

            float psum = 0.0f;
#pragma unroll
            for (int j = 0; j < 4; j++) {
                bf16x4 p4;
#pragma unroll
                for (int r = 0; r < 4; r++) {
                    float p = __expf(Sacc[j][r] - m_i);
                    psum += p;
                    p4[r] = (bf16)p;
                }
                int blk = (j * 2 + (qd >> 1)) ^ (ln & 7);
                *(bf16x4*)&sP[wave][ln * 64 + blk * 8 + (qd & 1) * 4] = p4;
            }
            psum += __shfl_xor(psum, 16);
            psum += __shfl_xor(psum, 32);
            l_i = l_i * alpha + psum;

            float a4[4];
#pragma unroll
            for (int r = 0; r < 4; r++) a4[r] = __shfl(alpha, (lane & 48) | (qd * 4 + r));
#pragma unroll
            for (int dt = 0; dt < 8; dt++)
#pragma unroll
                for (int r = 0; r < 4; r++) Oacc[dt][r] *= a4[r];

#pragma unroll
            for (int ks = 0; ks < 2; ks++) {
                bf16x8 pf = *(const bf16x8*)&sP[wave][ln * 64 + (((ks * 4 + qd) ^ (ln & 7)) * 8)];
#pragma unroll
                for (int dt = 0; dt < 8; dt++) {
                    bf16x8 vf = *(const bf16x8*)&sV[(dt * 16 + ln) * 64 + (((ks * 4 + qd) ^ (ln & 7)) * 8)];
                    Oacc[dt] = __builtin_amdgcn_mfma_f32_16x16x32_bf16(pf, vf, Oacc[dt], 0, 0, 0);
                }
            }
        }
        __syncthreads();
    }
    float linv[4];
#pragma unroll
    for (int r = 0; r < 4; r++)
        linv[r] = 1.0f / __shfl(l_i, (lane & 48) | (qd * 4 + r));
    bf16* Ob = O + (size_t)(qw + qd * 4) * 2048 + h * 128 + ln;
#pragma unroll
    for (int dt = 0; dt < 8; dt++)
#pragma unroll
        for (int r = 0; r < 4; r++)
            Ob[(size_t)r * 2048 + dt * 16] = (bf16)(Oacc[dt][r] * linv[r]);
}

extern "C" void kernel_launch(void* const* d_in, const int* in_sizes, int n_in,
                              void* d_out, int out_size, void* d_ws, size_t ws_size,
                              hipStream_t stream) {
    const float* X    = (const float*)d_in[0];  // [4096][2048] f32
    const float* Wqkv = (const float*)d_in[1];  // [6144][2048] f32
    const float* Wo   = (const float*)d_in[2];  // [2048][2048] f32
    float* out = (float*)d_out;                 // [4096][2048] f32
    bf16* QKV = (bf16*)d_ws;                    // [4096][6144] bf16
    bf16* ATT = QKV + (size_t)4096 * 6144;      // [4096][2048] bf16

    const size_t nX = (size_t)4096 * 2048, nWq = (size_t)6144 * 2048, nWo = (size_t)2048 * 2048;
    const size_t need = (nX * 3 + nWq * 2 + nWo) * 2 + nX * 2;  // QKV+ATT+Xb+Wqb+Wob (bytes)

    if (ws_size >= need) {
        bf16* Xb  = ATT + nX;
        bf16* Wqb = Xb + nX;
        bf16* Wob = Wqb + nWq;
        cast_f32_bf16<<<(int)(nX  / 8 / 256), 256, 0, stream>>>(X, Xb, (int)nX);
        cast_f32_bf16<<<(int)(nWq / 8 / 256), 256, 0, stream>>>(Wqkv, Wqb, (int)nWq);
        cast_f32_bf16<<<(int)(nWo / 8 / 256), 256, 0, stream>>>(Wo, Wob, (int)nWo);
        gemm_nt<0, 0, 0><<<dim3(32, 48), 256, 0, stream>>>(Xb, Wqb, QKV, 4096, 6144, 2048);
        rope_k<<<dim3(4096, 8), 256, 0, stream>>>(QKV);
        flash_attn<<<dim3(HNUM, 64), 256, 0, stream>>>(QKV, ATT);
        gemm_nt<0, 0, 1><<<dim3(32, 16), 256, 0, stream>>>(ATT, Wob, out, 4096, 2048, 2048);
    } else {
        gemm_nt<1, 1, 0><<<dim3(32, 48), 256, 0, stream>>>(X, Wqkv, QKV, 4096, 6144, 2048);
        rope_k<<<dim3(4096, 8), 256, 0, stream>>>(QKV);
        flash_attn<<<dim3(HNUM, 64), 256, 0, stream>>>(QKV, ATT);
        gemm_nt<0, 1, 1><<<dim3(32, 16), 256, 0, stream>>>(ATT, Wo, out, 4096, 2048, 2048);
    }
}